// Round 4
// baseline (207.380 us; speedup 1.0000x reference)
//
#include <hip/hip_runtime.h>

#define B_  2
#define Q_  2048
#define KV_ 2048
#define D_  1024
#define H_  16
#define DH_ 64

// 0.125 * log2(e): folded into qp so attention scores feed exp2 directly
#define QSCALE 0.18033688011112042f

using u16 = unsigned short;
using bf16x8 = __attribute__((ext_vector_type(8))) short;
using f32x4  = __attribute__((ext_vector_type(4))) float;

__device__ __forceinline__ u16 f2bf(float x) {
  unsigned u = __float_as_uint(x);
  u += 0x7fffu + ((u >> 16) & 1u);   // round-to-nearest-even
  return (u16)(u >> 16);
}

__device__ __forceinline__ void gl_lds16(const void* g, void* l) {
  __builtin_amdgcn_global_load_lds(
      (const __attribute__((address_space(1))) void*)g,
      (__attribute__((address_space(3))) void*)l, 16, 0, 0);
}

// T2 XOR-swizzle for a [R][64] bf16 LDS tile read as ds_read_b128 column slices.
// Logical (row, unit[0..7]) -> physical element offset. Involution: applied to
// the global SOURCE at staging time and to the LDS address at read time.
__device__ __forceinline__ int swz_off(int row, int unit) {
  return row * 64 + ((unit ^ (row & 7)) << 3);
}

#define MFMA16(a, b, c) __builtin_amdgcn_mfma_f32_16x16x32_bf16((a), (b), (c), 0, 0, 0)
#define EXP2F(x) __builtin_amdgcn_exp2f(x)

// ---------------------------------------------------------------------------
// Kernel 1: RMSNorm + bf16 cast for query (rows 0..4095) and key (rows 4096..8191)
// ---------------------------------------------------------------------------
__global__ __launch_bounds__(256) void k_rmsnorm_cast(
    const float* __restrict__ q, const float* __restrict__ k,
    const float* __restrict__ wq, const float* __restrict__ wk,
    u16* __restrict__ qn, u16* __restrict__ kn)
{
  const int row = blockIdx.x;
  const float* src; const float* w; u16* dst;
  if (row < B_ * Q_) {
    src = q + (size_t)row * D_; w = wq; dst = qn + (size_t)row * D_;
  } else {
    const int r2 = row - B_ * Q_;
    src = k + (size_t)r2 * D_; w = wk; dst = kn + (size_t)r2 * D_;
  }
  const int t = threadIdx.x;             // 256 threads, 4 floats each = 1024
  float4 v = reinterpret_cast<const float4*>(src)[t];
  float ss = v.x * v.x + v.y * v.y + v.z * v.z + v.w * v.w;
  #pragma unroll
  for (int off = 1; off < 64; off <<= 1) ss += __shfl_xor(ss, off);
  __shared__ float red[4];
  if ((t & 63) == 0) red[t >> 6] = ss;
  __syncthreads();
  const float tot = red[0] + red[1] + red[2] + red[3];
  const float sc = rsqrtf(tot * (1.0f / D_) + 1.1920929e-07f);
  float4 wv = reinterpret_cast<const float4*>(w)[t];
  ushort4 o;
  o.x = f2bf(v.x * sc * wv.x);
  o.y = f2bf(v.y * sc * wv.y);
  o.z = f2bf(v.z * sc * wv.z);
  o.w = f2bf(v.w * sc * wv.w);
  reinterpret_cast<ushort4*>(dst)[t] = o;
}

// ---------------------------------------------------------------------------
// Kernel 2: small prep — cast Wq|Wk to bf16 (blocks 0..2047) + stage biases
// ---------------------------------------------------------------------------
__global__ __launch_bounds__(256) void k_prep_small(
    const float* __restrict__ Wq, const float* __restrict__ Wk,
    const float* __restrict__ bq, const float* __restrict__ bk,
    u16* __restrict__ Wb, float* __restrict__ biasbuf)
{
  const int bid = blockIdx.x, t = threadIdx.x;
  if (bid < 2048) {
    const int i = bid * 256 + t;               // 0..524287 float4s
    const bool isK = i >= 262144;
    const int j = i & 262143;                  // index within one 1Mx float matrix
    float4 v = reinterpret_cast<const float4*>(isK ? Wk : Wq)[j];
    ushort4 o;
    o.x = f2bf(v.x); o.y = f2bf(v.y); o.z = f2bf(v.z); o.w = f2bf(v.w);
    reinterpret_cast<ushort4*>(Wb + (isK ? D_ * D_ : 0))[j] = o;
  } else {
    #pragma unroll
    for (int r = 0; r < 2; ++r) {
      const int i = r * 256 + t;               // 0..511 float4s (2048 floats)
      float4 v = (i < 256) ? reinterpret_cast<const float4*>(bq)[i]
                           : reinterpret_cast<const float4*>(bk)[i - 256];
      reinterpret_cast<float4*>(biasbuf)[i] = v;
    }
  }
}

// ---------------------------------------------------------------------------
// Kernel 3: value (B,KV,D) fp32 -> vT (B,D,KV) bf16, 64x64 LDS tiles
// ---------------------------------------------------------------------------
__global__ __launch_bounds__(256) void k_transpose_cast_v(
    const float* __restrict__ v, u16* __restrict__ vT)
{
  const int kv0 = blockIdx.x * 64, d0 = blockIdx.y * 64, b = blockIdx.z;
  __shared__ u16 tile[64][72];           // +8 pad breaks bank conflicts
  const int t = threadIdx.x;
  #pragma unroll
  for (int i = 0; i < 16; ++i) {
    const int idx = i * 256 + t, r = idx >> 6, c = idx & 63;
    tile[r][c] = f2bf(v[((size_t)b * KV_ + kv0 + r) * D_ + d0 + c]);
  }
  __syncthreads();
  #pragma unroll
  for (int i = 0; i < 16; ++i) {
    const int idx = i * 256 + t, r = idx >> 6, c = idx & 63;
    vT[((size_t)b * D_ + d0 + r) * KV_ + kv0 + c] = tile[c][r];
  }
}

// ---------------------------------------------------------------------------
// Kernel 4: C = A * B^T (+bias,*scale), bf16 in, fp32 accum. TM x TN tile,
// BK=64, 4 waves as 2x2, T2-swizzled LDS, T3 minimal 2-phase pipeline:
// double-buffered LDS, STAGE(next) issued before compute(cur), 1 barrier/tile.
// ---------------------------------------------------------------------------
template<int TM, int TN, bool OUT_BF16, bool PROJ>
__global__ __launch_bounds__(256) void k_gemm_bt(
    const u16* __restrict__ A, int lda, long sA,
    const u16* __restrict__ Bm, int ldb, long sB,
    void* __restrict__ C, int ldc, long sC,
    int K, const float* __restrict__ bias)
{
  constexpr int MR = TM / 32, NR = TN / 32;    // per-wave 16x16 frag repeats
  const int bb = blockIdx.z;
  const u16* Ab = A + (size_t)bb * sA;
  const u16* Bb = Bm + (size_t)bb * sB;
  const int row0 = blockIdx.y * TM, col0 = blockIdx.x * TN;
  __shared__ u16 As[2][TM * 64];
  __shared__ u16 Bs[2][TN * 64];
  const int tid = threadIdx.x, lane = tid & 63;
  const int w = tid >> 6, wm = w >> 1, wn = w & 1;
  const int lrow = lane & 15, sub = lane >> 4, lrow7 = lrow & 7;
  const f32x4 zero4 = {0.f, 0.f, 0.f, 0.f};
  f32x4 acc[MR][NR];
  #pragma unroll
  for (int m = 0; m < MR; ++m)
    #pragma unroll
    for (int n = 0; n < NR; ++n) acc[m][n] = zero4;

  const int nk = K >> 6;

#define GEMM_STAGE(buf, kt)                                                   \
  {                                                                           \
    const int k0 = (kt) << 6;                                                 \
    _Pragma("unroll")                                                         \
    for (int i = 0; i < TM / 32; ++i) {                                       \
      const int c = i * 256 + tid, r = c >> 3, u = (c & 7) ^ (r & 7);         \
      gl_lds16(Ab + (size_t)(row0 + r) * lda + k0 + u * 8, &As[buf][c * 8]);  \
    }                                                                         \
    _Pragma("unroll")                                                         \
    for (int i = 0; i < TN / 32; ++i) {                                       \
      const int c = i * 256 + tid, r = c >> 3, u = (c & 7) ^ (r & 7);         \
      gl_lds16(Bb + (size_t)(col0 + r) * ldb + k0 + u * 8, &Bs[buf][c * 8]);  \
    }                                                                         \
  }

  GEMM_STAGE(0, 0);
  int cur = 0;
  for (int kt = 0; kt < nk; ++kt) {
    __syncthreads();                       // drains vmcnt: buf[cur] ready
    if (kt + 1 < nk) GEMM_STAGE(cur ^ 1, kt + 1);
    #pragma unroll
    for (int ks = 0; ks < 2; ++ks) {
      bf16x8 af[MR], bfr[NR];
      #pragma unroll
      for (int m = 0; m < MR; ++m) {
        const int rA = wm * (TM / 2) + m * 16 + lrow;
        af[m] = *(const bf16x8*)&As[cur][rA * 64 + ((((ks << 2) + sub) ^ lrow7) << 3)];
      }
      #pragma unroll
      for (int n = 0; n < NR; ++n) {
        const int rB = wn * (TN / 2) + n * 16 + lrow;
        bfr[n] = *(const bf16x8*)&Bs[cur][rB * 64 + ((((ks << 2) + sub) ^ lrow7) << 3)];
      }
      #pragma unroll
      for (int m = 0; m < MR; ++m)
        #pragma unroll
        for (int n = 0; n < NR; ++n)
          acc[m][n] = MFMA16(af[m], bfr[n], acc[m][n]);
    }
    cur ^= 1;
  }
#undef GEMM_STAGE

  const int crow = sub * 4, ccol = lane & 15;
  const float scl = (PROJ && bb == 0) ? QSCALE : 1.0f;
  #pragma unroll
  for (int m = 0; m < MR; ++m) {
    #pragma unroll
    for (int n = 0; n < NR; ++n) {
      const int gcol = col0 + wn * (TN / 2) + n * 16 + ccol;
      const float badd = PROJ ? bias[bb * 1024 + gcol] : 0.0f;
      #pragma unroll
      for (int r = 0; r < 4; ++r) {
        const int grow = row0 + wm * (TM / 2) + m * 16 + crow + r;
        const float val = (acc[m][n][r] + badd) * scl;
        if (OUT_BF16)
          ((u16*)C)[(size_t)bb * sC + (size_t)grow * ldc + gcol] = f2bf(val);
        else
          ((float*)C)[(size_t)bb * sC + (size_t)grow * ldc + gcol] = val;
      }
    }
  }
}

// Stage one 128x64 bf16 K-tile (XOR-swizzled source) into Ks[buf]
#define STAGE_K(buf, kvbase, hh)                                              \
  {                                                                           \
    _Pragma("unroll")                                                         \
    for (int i = 0; i < 4; ++i) {                                             \
      const int c = i * 256 + tid, r = c >> 3, u = (c & 7) ^ (r & 7);         \
      gl_lds16(&kp[((size_t)b * KV_ + (kvbase) + r) * D_ + (hh) * 64 + u * 8],\
               &Ks[buf][c * 8]);                                              \
    }                                                                         \
  }

// ---------------------------------------------------------------------------
// Kernel 5 (pass A): Linv[b,h,i] = 1 / (H * sum_j 2^s(i,j))   (qp pre-scaled)
// block = (64 q-rows, head, batch); wave w owns kv slice [w*32, w*32+32) of
// each 128-tile x ALL 64 q-rows (no redundant LDS reads). q-frags hoisted.
// Double-buffered K staging; cross-wave LDS reduction at the end.
// ---------------------------------------------------------------------------
__global__ __launch_bounds__(256) void k_attn_rowsum(
    const u16* __restrict__ qp, const u16* __restrict__ kp,
    float* __restrict__ Linv)
{
  const int qb = blockIdx.x * 64, h = blockIdx.y, b = blockIdx.z;
  __shared__ u16 Ks[2][128 * 64];
  __shared__ float red[4][64];
  const int tid = threadIdx.x, lane = tid & 63, w = tid >> 6;
  const int lrow = lane & 15, sub = lane >> 4;

  // q fragments for all 64 q-rows (loop-invariant: h fixed per block)
  bf16x8 af[4][2];
  #pragma unroll
  for (int m = 0; m < 4; ++m)
    #pragma unroll
    for (int ks = 0; ks < 2; ++ks)
      af[m][ks] = *(const bf16x8*)&qp[((size_t)b * Q_ + qb + m * 16 + lrow) * D_
                                      + h * 64 + ks * 32 + sub * 8];
  const f32x4 zero4 = {0.f, 0.f, 0.f, 0.f};
  float lsum[4][4];
  #pragma unroll
  for (int m = 0; m < 4; ++m)
    #pragma unroll
    for (int r = 0; r < 4; ++r) lsum[m][r] = 0.f;

  STAGE_K(0, 0, h);
  int cur = 0;
  for (int kt = 0; kt < KV_ / 128; ++kt) {
    __syncthreads();
    if (kt + 1 < KV_ / 128) STAGE_K(cur ^ 1, (kt + 1) * 128, h);
    #pragma unroll
    for (int n = 0; n < 2; ++n) {
      const int row = w * 32 + n * 16 + lrow;
      const bf16x8 b0 = *(const bf16x8*)&Ks[cur][swz_off(row, sub)];
      const bf16x8 b1 = *(const bf16x8*)&Ks[cur][swz_off(row, 4 + sub)];
      #pragma unroll
      for (int m = 0; m < 4; ++m) {
        f32x4 s = zero4;
        s = MFMA16(af[m][0], b0, s);
        s = MFMA16(af[m][1], b1, s);
        #pragma unroll
        for (int r = 0; r < 4; ++r) lsum[m][r] += EXP2F(s[r]);
      }
    }
    cur ^= 1;
  }
  // reduce over the 16 columns held within each 16-lane group
  #pragma unroll
  for (int m = 0; m < 4; ++m)
    #pragma unroll
    for (int r = 0; r < 4; ++r) {
      #pragma unroll
      for (int off = 1; off < 16; off <<= 1)
        lsum[m][r] += __shfl_xor(lsum[m][r], off);
    }
  if (lrow == 0) {
    #pragma unroll
    for (int m = 0; m < 4; ++m)
      #pragma unroll
      for (int r = 0; r < 4; ++r) red[w][m * 16 + sub * 4 + r] = lsum[m][r];
  }
  __syncthreads();
  if (tid < 64) {
    const float s = red[0][tid] + red[1][tid] + red[2][tid] + red[3][tid];
    Linv[((size_t)b * H_ + h) * Q_ + qb + tid] = 1.0f / (s * (float)H_);
  }
}

// ---------------------------------------------------------------------------
// Kernel 6 (pass B): attn[b,i,j] = sum_h 2^s_h(i,j) * Linv[b,h,i]
// block = (64 q-rows, 128 kv-cols, batch); wave w owns kv slice [w*32,w*32+32)
// x ALL 64 q-rows. Heads looped with double-buffered K staging.
// ---------------------------------------------------------------------------
__global__ __launch_bounds__(256) void k_attn_weights(
    const u16* __restrict__ qp, const u16* __restrict__ kp,
    const float* __restrict__ Linv, u16* __restrict__ attn)
{
  const int kv0 = blockIdx.x * 128, qb = blockIdx.y * 64, b = blockIdx.z;
  __shared__ u16 Ks[2][128 * 64];
  const int tid = threadIdx.x, lane = tid & 63, w = tid >> 6;
  const int lrow = lane & 15, sub = lane >> 4;
  const f32x4 zero4 = {0.f, 0.f, 0.f, 0.f};
  f32x4 acc[4][2];
  #pragma unroll
  for (int m = 0; m < 4; ++m)
    #pragma unroll
    for (int n = 0; n < 2; ++n) acc[m][n] = zero4;

  STAGE_K(0, kv0, 0);
  int cur = 0;
  for (int h = 0; h < H_; ++h) {
    __syncthreads();                       // buf[cur] ready; joins waves
    // q fragments + Linv for this head (issued before next stage: oldest vmem)
    bf16x8 af[4][2];
    #pragma unroll
    for (int m = 0; m < 4; ++m)
      #pragma unroll
      for (int ks = 0; ks < 2; ++ks)
        af[m][ks] = *(const bf16x8*)&qp[((size_t)b * Q_ + qb + m * 16 + lrow) * D_
                                        + h * 64 + ks * 32 + sub * 8];
    f32x4 lv[4];
    #pragma unroll
    for (int m = 0; m < 4; ++m)
      lv[m] = *(const f32x4*)&Linv[((size_t)b * H_ + h) * Q_ + qb + m * 16 + sub * 4];
    if (h + 1 < H_) STAGE_K(cur ^ 1, kv0, h + 1);
    #pragma unroll
    for (int n = 0; n < 2; ++n) {
      const int row = w * 32 + n * 16 + lrow;
      const bf16x8 b0 = *(const bf16x8*)&Ks[cur][swz_off(row, sub)];
      const bf16x8 b1 = *(const bf16x8*)&Ks[cur][swz_off(row, 4 + sub)];
      #pragma unroll
      for (int m = 0; m < 4; ++m) {
        f32x4 s = zero4;
        s = MFMA16(af[m][0], b0, s);
        s = MFMA16(af[m][1], b1, s);
        #pragma unroll
        for (int r = 0; r < 4; ++r) acc[m][n][r] += EXP2F(s[r]) * lv[m][r];
      }
    }
    cur ^= 1;
  }
  #pragma unroll
  for (int m = 0; m < 4; ++m) {
    #pragma unroll
    for (int n = 0; n < 2; ++n) {
      const int gcol = kv0 + w * 32 + n * 16 + (lane & 15);
      #pragma unroll
      for (int r = 0; r < 4; ++r) {
        const int grow = qb + m * 16 + sub * 4 + r;
        attn[((size_t)b * Q_ + grow) * KV_ + gcol] = f2bf(acc[m][n][r]);
      }
    }
  }
}

// ---------------------------------------------------------------------------
// Launch
// ---------------------------------------------------------------------------
extern "C" void kernel_launch(void* const* d_in, const int* in_sizes, int n_in,
                              void* d_out, int out_size, void* d_ws, size_t ws_size,
                              hipStream_t stream)
{
  (void)in_sizes; (void)n_in; (void)out_size; (void)ws_size;
  const float* query = (const float*)d_in[0];
  const float* key   = (const float*)d_in[1];
  const float* value = (const float*)d_in[2];
  const float* wqn   = (const float*)d_in[3];
  const float* wkn   = (const float*)d_in[4];
  const float* Wq    = (const float*)d_in[5];
  const float* Wk    = (const float*)d_in[6];
  const float* bq    = (const float*)d_in[7];
  const float* bk    = (const float*)d_in[8];
  float* out = (float*)d_out;

  // workspace layout (~46.7 MB; attn aliases the dead qn+kn region)
  char* ws = (char*)d_ws;
  u16* qn   = (u16*)(ws);                 //  8 MiB  (B*Q, D)  bf16
  u16* attn = (u16*)(ws);                 // 16 MiB  (B, Q, KV) bf16 — alias qn+kn
  u16* qp   = (u16*)(ws + 16777216);      //  8 MiB  (B*Q, D)  bf16
  u16* kp   = (u16*)(ws + 25165824);      //  8 MiB  (B*KV, D) bf16
  u16* Wqb  = (u16*)(ws + 33554432);      //  4 MiB  (2, D, D) bf16 (Wq|Wk adjacent)
  u16* vT   = (u16*)(ws + 37748736);      //  8 MiB  (B, D, KV) bf16
  float* Linv = (float*)(ws + 46137344);  // 256 KiB (B, H, Q) fp32
  float* biasbuf = (float*)(ws + 46399488); // 8 KiB (2, D) fp32
  u16* kn = qn + 4194304;

  k_rmsnorm_cast<<<dim3(B_ * Q_ + B_ * KV_), dim3(256), 0, stream>>>(
      query, key, wqn, wkn, qn, kn);
  k_prep_small<<<dim3(2049), dim3(256), 0, stream>>>(Wq, Wk, bq, bk, Wqb, biasbuf);
  k_transpose_cast_v<<<dim3(KV_ / 64, D_ / 64, B_), dim3(256), 0, stream>>>(value, vT);

  // batched projections: z=0 -> qp = (qn@Wq^T + bq)*QSCALE ; z=1 -> kp = kn@Wk^T + bk
  k_gemm_bt<128, 128, true, true>
      <<<dim3(D_ / 128, (B_ * Q_) / 128, 2), dim3(256), 0, stream>>>(
      qn, D_, 4194304, Wqb, D_, 1048576, qp, D_, 4194304, D_, biasbuf);

  k_attn_rowsum<<<dim3(Q_ / 64, H_, B_), dim3(256), 0, stream>>>(qp, kp, Linv);
  k_attn_weights<<<dim3(KV_ / 128, Q_ / 64, B_), dim3(256), 0, stream>>>(qp, kp, Linv, attn);

  // PV: out[b] = attn[b] @ vT[b]^T, 128x64 tiles -> 512 blocks (2/CU)
  k_gemm_bt<128, 64, false, false>
      <<<dim3(D_ / 64, Q_ / 128, B_), dim3(256), 0, stream>>>(
      attn, KV_, (long)Q_ * KV_, vT, KV_, (long)D_ * KV_,
      out, D_, (long)Q_ * D_, KV_, nullptr);
}

// Round 5
// 159.536 us; speedup vs baseline: 1.2999x; 1.2999x over previous
//
#include <hip/hip_runtime.h>

#define B_  2
#define Q_  2048
#define KV_ 2048
#define D_  1024
#define H_  16
#define DH_ 64

// 0.125 * log2(e): folded into qp so attention scores feed exp2 directly
#define QSCALE 0.18033688011112042f

using u16 = unsigned short;
using bf16x8 = __attribute__((ext_vector_type(8))) short;
using f32x4  = __attribute__((ext_vector_type(4))) float;

__device__ __forceinline__ u16 f2bf(float x) {
  unsigned u = __float_as_uint(x);
  u += 0x7fffu + ((u >> 16) & 1u);   // round-to-nearest-even
  return (u16)(u >> 16);
}

__device__ __forceinline__ void gl_lds16(const void* g, void* l) {
  __builtin_amdgcn_global_load_lds(
      (const __attribute__((address_space(1))) void*)g,
      (__attribute__((address_space(3))) void*)l, 16, 0, 0);
}

// T2 XOR-swizzle for a [R][64] bf16 LDS tile read as ds_read_b128 column slices.
// Logical (row, unit[0..7]) -> physical element offset. Involution: applied to
// the global SOURCE at staging time and to the LDS address at read time.
__device__ __forceinline__ int swz_off(int row, int unit) {
  return row * 64 + ((unit ^ (row & 7)) << 3);
}

#define MFMA16(a, b, c) __builtin_amdgcn_mfma_f32_16x16x32_bf16((a), (b), (c), 0, 0, 0)
#define EXP2F(x) __builtin_amdgcn_exp2f(x)

// ---------------------------------------------------------------------------
// Kernel 1: RMSNorm + bf16 cast for query (rows 0..4095) and key (rows 4096..8191)
// ---------------------------------------------------------------------------
__global__ __launch_bounds__(256) void k_rmsnorm_cast(
    const float* __restrict__ q, const float* __restrict__ k,
    const float* __restrict__ wq, const float* __restrict__ wk,
    u16* __restrict__ qn, u16* __restrict__ kn)
{
  const int row = blockIdx.x;
  const float* src; const float* w; u16* dst;
  if (row < B_ * Q_) {
    src = q + (size_t)row * D_; w = wq; dst = qn + (size_t)row * D_;
  } else {
    const int r2 = row - B_ * Q_;
    src = k + (size_t)r2 * D_; w = wk; dst = kn + (size_t)r2 * D_;
  }
  const int t = threadIdx.x;             // 256 threads, 4 floats each = 1024
  float4 v = reinterpret_cast<const float4*>(src)[t];
  float ss = v.x * v.x + v.y * v.y + v.z * v.z + v.w * v.w;
  #pragma unroll
  for (int off = 1; off < 64; off <<= 1) ss += __shfl_xor(ss, off);
  __shared__ float red[4];
  if ((t & 63) == 0) red[t >> 6] = ss;
  __syncthreads();
  const float tot = red[0] + red[1] + red[2] + red[3];
  const float sc = rsqrtf(tot * (1.0f / D_) + 1.1920929e-07f);
  float4 wv = reinterpret_cast<const float4*>(w)[t];
  ushort4 o;
  o.x = f2bf(v.x * sc * wv.x);
  o.y = f2bf(v.y * sc * wv.y);
  o.z = f2bf(v.z * sc * wv.z);
  o.w = f2bf(v.w * sc * wv.w);
  reinterpret_cast<ushort4*>(dst)[t] = o;
}

// ---------------------------------------------------------------------------
// Kernel 2: small prep — cast Wq|Wk to bf16 (blocks 0..2047) + stage biases
// ---------------------------------------------------------------------------
__global__ __launch_bounds__(256) void k_prep_small(
    const float* __restrict__ Wq, const float* __restrict__ Wk,
    const float* __restrict__ bq, const float* __restrict__ bk,
    u16* __restrict__ Wb, float* __restrict__ biasbuf)
{
  const int bid = blockIdx.x, t = threadIdx.x;
  if (bid < 2048) {
    const int i = bid * 256 + t;               // 0..524287 float4s
    const bool isK = i >= 262144;
    const int j = i & 262143;                  // index within one 1Mx float matrix
    float4 v = reinterpret_cast<const float4*>(isK ? Wk : Wq)[j];
    ushort4 o;
    o.x = f2bf(v.x); o.y = f2bf(v.y); o.z = f2bf(v.z); o.w = f2bf(v.w);
    reinterpret_cast<ushort4*>(Wb + (isK ? D_ * D_ : 0))[j] = o;
  } else {
    #pragma unroll
    for (int r = 0; r < 2; ++r) {
      const int i = r * 256 + t;               // 0..511 float4s (2048 floats)
      float4 v = (i < 256) ? reinterpret_cast<const float4*>(bq)[i]
                           : reinterpret_cast<const float4*>(bk)[i - 256];
      reinterpret_cast<float4*>(biasbuf)[i] = v;
    }
  }
}

// ---------------------------------------------------------------------------
// Kernel 3: value (B,KV,D) fp32 -> vT (B,D,KV) bf16, 64x64 LDS tiles
// ---------------------------------------------------------------------------
__global__ __launch_bounds__(256) void k_transpose_cast_v(
    const float* __restrict__ v, u16* __restrict__ vT)
{
  const int kv0 = blockIdx.x * 64, d0 = blockIdx.y * 64, b = blockIdx.z;
  __shared__ u16 tile[64][72];           // +8 pad breaks bank conflicts
  const int t = threadIdx.x;
  #pragma unroll
  for (int i = 0; i < 16; ++i) {
    const int idx = i * 256 + t, r = idx >> 6, c = idx & 63;
    tile[r][c] = f2bf(v[((size_t)b * KV_ + kv0 + r) * D_ + d0 + c]);
  }
  __syncthreads();
  #pragma unroll
  for (int i = 0; i < 16; ++i) {
    const int idx = i * 256 + t, r = idx >> 6, c = idx & 63;
    vT[((size_t)b * D_ + d0 + r) * KV_ + kv0 + c] = tile[c][r];
  }
}

// ---------------------------------------------------------------------------
// Kernel 4: C = A * B^T (+bias,*scale), bf16 in, fp32 accum. TM x TN tile,
// BK=64, 4 waves as 2x2, T2-swizzled LDS, T3 minimal 2-phase pipeline:
// double-buffered LDS, STAGE(next) issued before compute(cur), 1 barrier/tile.
// ---------------------------------------------------------------------------
template<int TM, int TN, bool OUT_BF16, bool PROJ>
__global__ __launch_bounds__(256) void k_gemm_bt(
    const u16* __restrict__ A, int lda, long sA,
    const u16* __restrict__ Bm, int ldb, long sB,
    void* __restrict__ C, int ldc, long sC,
    int K, const float* __restrict__ bias)
{
  constexpr int MR = TM / 32, NR = TN / 32;    // per-wave 16x16 frag repeats
  const int bb = blockIdx.z;
  const u16* Ab = A + (size_t)bb * sA;
  const u16* Bb = Bm + (size_t)bb * sB;
  const int row0 = blockIdx.y * TM, col0 = blockIdx.x * TN;
  __shared__ u16 As[2][TM * 64];
  __shared__ u16 Bs[2][TN * 64];
  const int tid = threadIdx.x, lane = tid & 63;
  const int w = tid >> 6, wm = w >> 1, wn = w & 1;
  const int lrow = lane & 15, sub = lane >> 4, lrow7 = lrow & 7;
  const f32x4 zero4 = {0.f, 0.f, 0.f, 0.f};
  f32x4 acc[MR][NR];
  #pragma unroll
  for (int m = 0; m < MR; ++m)
    #pragma unroll
    for (int n = 0; n < NR; ++n) acc[m][n] = zero4;

  const int nk = K >> 6;

#define GEMM_STAGE(buf, kt)                                                   \
  {                                                                           \
    const int k0 = (kt) << 6;                                                 \
    _Pragma("unroll")                                                         \
    for (int i = 0; i < TM / 32; ++i) {                                       \
      const int c = i * 256 + tid, r = c >> 3, u = (c & 7) ^ (r & 7);         \
      gl_lds16(Ab + (size_t)(row0 + r) * lda + k0 + u * 8, &As[buf][c * 8]);  \
    }                                                                         \
    _Pragma("unroll")                                                         \
    for (int i = 0; i < TN / 32; ++i) {                                       \
      const int c = i * 256 + tid, r = c >> 3, u = (c & 7) ^ (r & 7);         \
      gl_lds16(Bb + (size_t)(col0 + r) * ldb + k0 + u * 8, &Bs[buf][c * 8]);  \
    }                                                                         \
  }

  GEMM_STAGE(0, 0);
  int cur = 0;
  for (int kt = 0; kt < nk; ++kt) {
    __syncthreads();                       // drains vmcnt: buf[cur] ready
    if (kt + 1 < nk) GEMM_STAGE(cur ^ 1, kt + 1);
    #pragma unroll
    for (int ks = 0; ks < 2; ++ks) {
      bf16x8 af[MR], bfr[NR];
      #pragma unroll
      for (int m = 0; m < MR; ++m) {
        const int rA = wm * (TM / 2) + m * 16 + lrow;
        af[m] = *(const bf16x8*)&As[cur][rA * 64 + ((((ks << 2) + sub) ^ lrow7) << 3)];
      }
      #pragma unroll
      for (int n = 0; n < NR; ++n) {
        const int rB = wn * (TN / 2) + n * 16 + lrow;
        bfr[n] = *(const bf16x8*)&Bs[cur][rB * 64 + ((((ks << 2) + sub) ^ lrow7) << 3)];
      }
      #pragma unroll
      for (int m = 0; m < MR; ++m)
        #pragma unroll
        for (int n = 0; n < NR; ++n)
          acc[m][n] = MFMA16(af[m], bfr[n], acc[m][n]);
    }
    cur ^= 1;
  }
#undef GEMM_STAGE

  const int crow = sub * 4, ccol = lane & 15;
  const float scl = (PROJ && bb == 0) ? QSCALE : 1.0f;
  #pragma unroll
  for (int m = 0; m < MR; ++m) {
    #pragma unroll
    for (int n = 0; n < NR; ++n) {
      const int gcol = col0 + wn * (TN / 2) + n * 16 + ccol;
      const float badd = PROJ ? bias[bb * 1024 + gcol] : 0.0f;
      #pragma unroll
      for (int r = 0; r < 4; ++r) {
        const int grow = row0 + wm * (TM / 2) + m * 16 + crow + r;
        const float val = (acc[m][n][r] + badd) * scl;
        if (OUT_BF16)
          ((u16*)C)[(size_t)bb * sC + (size_t)grow * ldc + gcol] = f2bf(val);
        else
          ((float*)C)[(size_t)bb * sC + (size_t)grow * ldc + gcol] = val;
      }
    }
  }
}

// Stage one 128x64 bf16 K-tile (XOR-swizzled source) into Ks[buf]
#define STAGE_K(buf, kvbase, hh)                                              \
  {                                                                           \
    _Pragma("unroll")                                                         \
    for (int i = 0; i < 4; ++i) {                                             \
      const int c = i * 256 + tid, r = c >> 3, u = (c & 7) ^ (r & 7);         \
      gl_lds16(&kp[((size_t)b * KV_ + (kvbase) + r) * D_ + (hh) * 64 + u * 8],\
               &Ks[buf][c * 8]);                                              \
    }                                                                         \
  }

// ---------------------------------------------------------------------------
// Kernel 5 (pass A): Linv[b,h,i] = 1 / (H * sum_j 2^s(i,j))   (qp pre-scaled)
// block = (64 q-rows, head, batch); wave w owns kv slice [w*32, w*32+32) of
// each 128-tile x ALL 64 q-rows. q-frags hoisted (loop-invariant).
// ---------------------------------------------------------------------------
__global__ __launch_bounds__(256) void k_attn_rowsum(
    const u16* __restrict__ qp, const u16* __restrict__ kp,
    float* __restrict__ Linv)
{
  const int qb = blockIdx.x * 64, h = blockIdx.y, b = blockIdx.z;
  __shared__ u16 Ks[2][128 * 64];
  __shared__ float red[4][64];
  const int tid = threadIdx.x, lane = tid & 63, w = tid >> 6;
  const int lrow = lane & 15, sub = lane >> 4;

  // q fragments for all 64 q-rows (loop-invariant: h fixed per block)
  bf16x8 af[4][2];
  #pragma unroll
  for (int m = 0; m < 4; ++m)
    #pragma unroll
    for (int ks = 0; ks < 2; ++ks)
      af[m][ks] = *(const bf16x8*)&qp[((size_t)b * Q_ + qb + m * 16 + lrow) * D_
                                      + h * 64 + ks * 32 + sub * 8];
  const f32x4 zero4 = {0.f, 0.f, 0.f, 0.f};
  float lsum[4][4];
  #pragma unroll
  for (int m = 0; m < 4; ++m)
    #pragma unroll
    for (int r = 0; r < 4; ++r) lsum[m][r] = 0.f;

  STAGE_K(0, 0, h);
  int cur = 0;
  for (int kt = 0; kt < KV_ / 128; ++kt) {
    __syncthreads();
    if (kt + 1 < KV_ / 128) STAGE_K(cur ^ 1, (kt + 1) * 128, h);
    #pragma unroll
    for (int n = 0; n < 2; ++n) {
      const int row = w * 32 + n * 16 + lrow;
      const bf16x8 b0 = *(const bf16x8*)&Ks[cur][swz_off(row, sub)];
      const bf16x8 b1 = *(const bf16x8*)&Ks[cur][swz_off(row, 4 + sub)];
      #pragma unroll
      for (int m = 0; m < 4; ++m) {
        f32x4 s = zero4;
        s = MFMA16(af[m][0], b0, s);
        s = MFMA16(af[m][1], b1, s);
        #pragma unroll
        for (int r = 0; r < 4; ++r) lsum[m][r] += EXP2F(s[r]);
      }
    }
    cur ^= 1;
  }
  // reduce over the 16 columns held within each 16-lane group
  #pragma unroll
  for (int m = 0; m < 4; ++m)
    #pragma unroll
    for (int r = 0; r < 4; ++r) {
      #pragma unroll
      for (int off = 1; off < 16; off <<= 1)
        lsum[m][r] += __shfl_xor(lsum[m][r], off);
    }
  if (lrow == 0) {
    #pragma unroll
    for (int m = 0; m < 4; ++m)
      #pragma unroll
      for (int r = 0; r < 4; ++r) red[w][m * 16 + sub * 4 + r] = lsum[m][r];
  }
  __syncthreads();
  if (tid < 64) {
    const float s = red[0][tid] + red[1][tid] + red[2][tid] + red[3][tid];
    Linv[((size_t)b * H_ + h) * Q_ + qb + tid] = 1.0f / (s * (float)H_);
  }
}

// ---------------------------------------------------------------------------
// Kernel 6 (pass B): attn[b,i,j] = sum_h 2^s_h(i,j) * Linv[b,h,i]
// block = (64 q-rows, 128 kv-cols, batch); wave grid 2x2: wm owns 32 q-rows,
// wn owns 64 kv-cols. Head loop unrolled x2 with static register ping-pong:
// head h+1's q-frags/Linv are prefetched while head h computes, so the MFMA
// cluster never waits on same-iteration global gathers. Dbuf K staging.
// ---------------------------------------------------------------------------
__global__ __launch_bounds__(256, 2) void k_attn_weights(
    const u16* __restrict__ qp, const u16* __restrict__ kp,
    const float* __restrict__ Linv, u16* __restrict__ attn)
{
  const int kv0 = blockIdx.x * 128, qb = blockIdx.y * 64, b = blockIdx.z;
  __shared__ u16 Ks[2][128 * 64];
  const int tid = threadIdx.x, lane = tid & 63, w = tid >> 6;
  const int wm = w >> 1, wn = w & 1;
  const int lrow = lane & 15, sub = lane >> 4;
  const f32x4 zero4 = {0.f, 0.f, 0.f, 0.f};
  f32x4 acc[2][4];
  #pragma unroll
  for (int m = 0; m < 2; ++m)
    #pragma unroll
    for (int n = 0; n < 4; ++n) acc[m][n] = zero4;

#define LOAD_AF(dst_af, dst_lv, hh)                                           \
  {                                                                           \
    _Pragma("unroll")                                                         \
    for (int m = 0; m < 2; ++m) {                                             \
      _Pragma("unroll")                                                       \
      for (int ks = 0; ks < 2; ++ks)                                          \
        dst_af[m][ks] = *(const bf16x8*)&qp[((size_t)b * Q_ + qb + wm * 32 +  \
            m * 16 + lrow) * D_ + (hh) * 64 + ks * 32 + sub * 8];             \
      dst_lv[m] = *(const f32x4*)&Linv[((size_t)b * H_ + (hh)) * Q_ + qb +    \
            wm * 32 + m * 16 + sub * 4];                                      \
    }                                                                         \
  }

#define COMPUTE_HALF(afX, lvX, buf)                                           \
  {                                                                           \
    _Pragma("unroll")                                                         \
    for (int n = 0; n < 4; ++n) {                                             \
      const int row = wn * 64 + n * 16 + lrow;                                \
      const bf16x8 bk0 = *(const bf16x8*)&Ks[buf][swz_off(row, sub)];         \
      const bf16x8 bk1 = *(const bf16x8*)&Ks[buf][swz_off(row, 4 + sub)];     \
      _Pragma("unroll")                                                       \
      for (int m = 0; m < 2; ++m) {                                           \
        f32x4 s = zero4;                                                      \
        s = MFMA16(afX[m][0], bk0, s);                                        \
        s = MFMA16(afX[m][1], bk1, s);                                        \
        _Pragma("unroll")                                                     \
        for (int r = 0; r < 4; ++r)                                           \
          acc[m][n][r] += EXP2F(s[r]) * lvX[m][r];                            \
      }                                                                       \
    }                                                                         \
  }

  bf16x8 afA[2][2], afB[2][2];
  f32x4 lvA[2], lvB[2];
  STAGE_K(0, kv0, 0);
  LOAD_AF(afA, lvA, 0);
  for (int hp = 0; hp < 8; ++hp) {
    const int h0 = hp * 2;
    __syncthreads();                     // Ks[0] (head h0) staged & visible
    STAGE_K(1, kv0, h0 + 1);
    LOAD_AF(afB, lvB, h0 + 1);           // prefetch next head's state
    COMPUTE_HALF(afA, lvA, 0);
    __syncthreads();                     // Ks[1] (head h0+1) ready
    if (hp < 7) {
      STAGE_K(0, kv0, h0 + 2);
      LOAD_AF(afA, lvA, h0 + 2);
    }
    COMPUTE_HALF(afB, lvB, 1);
  }
#undef LOAD_AF
#undef COMPUTE_HALF

  #pragma unroll
  for (int m = 0; m < 2; ++m) {
    #pragma unroll
    for (int n = 0; n < 4; ++n) {
      const int gcol = kv0 + wn * 64 + n * 16 + lrow;
      #pragma unroll
      for (int r = 0; r < 4; ++r) {
        const int grow = qb + wm * 32 + m * 16 + sub * 4 + r;
        attn[((size_t)b * Q_ + grow) * KV_ + gcol] = f2bf(acc[m][n][r]);
      }
    }
  }
}

// ---------------------------------------------------------------------------
// Launch
// ---------------------------------------------------------------------------
extern "C" void kernel_launch(void* const* d_in, const int* in_sizes, int n_in,
                              void* d_out, int out_size, void* d_ws, size_t ws_size,
                              hipStream_t stream)
{
  (void)in_sizes; (void)n_in; (void)out_size; (void)ws_size;
  const float* query = (const float*)d_in[0];
  const float* key   = (const float*)d_in[1];
  const float* value = (const float*)d_in[2];
  const float* wqn   = (const float*)d_in[3];
  const float* wkn   = (const float*)d_in[4];
  const float* Wq    = (const float*)d_in[5];
  const float* Wk    = (const float*)d_in[6];
  const float* bq    = (const float*)d_in[7];
  const float* bk    = (const float*)d_in[8];
  float* out = (float*)d_out;

  // workspace layout (~46.7 MB; attn aliases the dead qn+kn region)
  char* ws = (char*)d_ws;
  u16* qn   = (u16*)(ws);                 //  8 MiB  (B*Q, D)  bf16
  u16* attn = (u16*)(ws);                 // 16 MiB  (B, Q, KV) bf16 — alias qn+kn
  u16* qp   = (u16*)(ws + 16777216);      //  8 MiB  (B*Q, D)  bf16
  u16* kp   = (u16*)(ws + 25165824);      //  8 MiB  (B*KV, D) bf16
  u16* Wqb  = (u16*)(ws + 33554432);      //  4 MiB  (2, D, D) bf16 (Wq|Wk adjacent)
  u16* vT   = (u16*)(ws + 37748736);      //  8 MiB  (B, D, KV) bf16
  float* Linv = (float*)(ws + 46137344);  // 256 KiB (B, H, Q) fp32
  float* biasbuf = (float*)(ws + 46399488); // 8 KiB (2, D) fp32
  u16* kn = qn + 4194304;

  k_rmsnorm_cast<<<dim3(B_ * Q_ + B_ * KV_), dim3(256), 0, stream>>>(
      query, key, wqn, wkn, qn, kn);
  k_prep_small<<<dim3(2049), dim3(256), 0, stream>>>(Wq, Wk, bq, bk, Wqb, biasbuf);
  k_transpose_cast_v<<<dim3(KV_ / 64, D_ / 64, B_), dim3(256), 0, stream>>>(value, vT);

  // batched projections: z=0 -> qp = (qn@Wq^T + bq)*QSCALE ; z=1 -> kp = kn@Wk^T + bk
  k_gemm_bt<128, 128, true, true>
      <<<dim3(D_ / 128, (B_ * Q_) / 128, 2), dim3(256), 0, stream>>>(
      qn, D_, 4194304, Wqb, D_, 1048576, qp, D_, 4194304, D_, biasbuf);

  k_attn_rowsum<<<dim3(Q_ / 64, H_, B_), dim3(256), 0, stream>>>(qp, kp, Linv);
  k_attn_weights<<<dim3(KV_ / 128, Q_ / 64, B_), dim3(256), 0, stream>>>(qp, kp, Linv, attn);

  // PV: out[b] = attn[b] @ vT[b]^T, 128x64 tiles -> 512 blocks (2/CU)
  k_gemm_bt<128, 64, false, false>
      <<<dim3(D_ / 64, Q_ / 128, B_), dim3(256), 0, stream>>>(
      attn, KV_, (long)Q_ * KV_, vT, KV_, (long)D_ * KV_,
      out, D_, (long)Q_ * D_, KV_, nullptr);
}